// Round 1
// baseline (614.039 us; speedup 1.0000x reference)
//
#include <hip/hip_runtime.h>
#include <hip/hip_bf16.h>

typedef __attribute__((ext_vector_type(8))) short short8;
typedef __attribute__((ext_vector_type(4))) float f32x4;
typedef const __attribute__((address_space(1))) void GVOID;
typedef __attribute__((address_space(3))) void LVOID;

#define DI __device__ __forceinline__

DI unsigned short f2b(float f){
  union{float ff; unsigned u;} v; v.ff=f;
  unsigned r = v.u;
  r += 0x7fffu + ((r>>16)&1u);   // RNE
  return (unsigned short)(r>>16);
}
DI float b2f(unsigned short h){
  union{unsigned u; float ff;} v; v.u = ((unsigned)h)<<16; return v.ff;
}

DI void glds16(const void* g, void* l){
  __builtin_amdgcn_global_load_lds((GVOID*)g, (LVOID*)l, 16, 0, 0);
}

DI float dot8(short8 wv, const float* x){
  float s = 0.f;
  #pragma unroll
  for (int i=0;i<8;++i) s += b2f((unsigned short)wv[i]) * x[i];
  return s;
}

// block-wide (256 thr) sum of two values
DI void bred2(float& a, float& b, float* red){
  #pragma unroll
  for (int o=32;o>0;o>>=1){ a += __shfl_xor(a,o); b += __shfl_xor(b,o); }
  int wid = threadIdx.x>>6;
  __syncthreads();
  if ((threadIdx.x&63)==0){ red[wid*2]=a; red[wid*2+1]=b; }
  __syncthreads();
  a = red[0]+red[2]+red[4]+red[6];
  b = red[1]+red[3]+red[5]+red[7];
}

// ---------------- k_prep: weight conversion ----------------
// part A (blocks 0..255): Wk|Wv -> Wswz [512][256] bf16, columns XOR-swizzled
//   (16B chunk index ^ (row&7)) so k1 can global_load_lds linearly.
// part B (blocks 256..831): flat bf16 copies of Wih, Whh, W1, W2, Wq.
__global__ void k_prep(const float* __restrict__ Wk, const float* __restrict__ Wv,
                       const float* __restrict__ Wih, const float* __restrict__ Whh,
                       const float* __restrict__ W1, const float* __restrict__ W2,
                       const float* __restrict__ Wq,
                       unsigned short* Wswz, unsigned short* Wihb, unsigned short* Whhb,
                       unsigned short* W1b, unsigned short* W2b, unsigned short* Wqb){
  int t = threadIdx.x, blk = blockIdx.x;
  if (blk < 256){
    int row = blk*2 + (t>>7);
    int e0 = (t&127)*2;
    const float* src = (row < 256) ? (Wk + row*256 + e0) : (Wv + (row-256)*256 + e0);
    float a = src[0], b = src[1];
    int dst = (((e0>>3) ^ (row&7))<<3) + (e0&7);
    Wswz[row*256 + dst]     = f2b(a);
    Wswz[row*256 + dst + 1] = f2b(b);
  } else {
    int j = (blk-256)*1024 + t*4;
    const float* s; unsigned short* d; int off;
    if (j < 196608){ s=Wih; d=Wihb; off=j; }
    else if (j < 393216){ s=Whh; d=Whhb; off=j-196608; }
    else if (j < 458752){ s=W1;  d=W1b;  off=j-393216; }
    else if (j < 524288){ s=W2;  d=W2b;  off=j-458752; }
    else               { s=Wq;  d=Wqb;  off=j-524288; }
    float4 v = *(const float4*)(s+off);
    d[off]=f2b(v.x); d[off+1]=f2b(v.y); d[off+2]=f2b(v.z); d[off+3]=f2b(v.w);
  }
}

// ---------------- k_init: slots init + LN + q0, zero U/S/qpad ----------------
// grid 256 (one block per slot-row), 256 threads (t = d index and out index)
__global__ void k_init(const float* __restrict__ noise, const float* __restrict__ mu,
                       const float* __restrict__ ls, const float* __restrict__ lnsg,
                       const float* __restrict__ lnsb, const unsigned short* __restrict__ Wqb,
                       float* slots, float* U, float* S, unsigned short* qbuf){
  __shared__ __align__(16) float sn[256];
  __shared__ float red[8];
  int r = blockIdx.x, t = threadIdx.x;
  int b = r>>3, k = r&7;
  float val = mu[t] + __expf(ls[t]) * noise[r*256 + t];
  slots[r*256 + t] = val;
  U[r*256 + t] = 0.f;
  if (t == 0) S[r] = 0.f;
  qbuf[(b*16 + 8 + k)*256 + t] = 0;        // zero q pad row (slots 8..15)
  float sa = val, sb = val*val;
  bred2(sa, sb, red);
  float m = sa*(1.f/256.f);
  float var = sb*(1.f/256.f) - m*m;
  float inv = rsqrtf(fmaxf(var, 0.f) + 1e-5f);
  sn[t] = (val - m)*inv*lnsg[t] + lnsb[t];
  __syncthreads();
  const unsigned short* wr = Wqb + (size_t)t*256;
  float acc = 0.f;
  #pragma unroll 4
  for (int c=0;c<32;++c) acc += dot8(*(const short8*)(wr + c*8), sn + c*8);
  qbuf[(b*16 + k)*256 + t] = f2b(acc * 0.0625f);   // SCALE = D^-0.5 folded in
}

// ---------------- k1: LN(embeddings) + keys/values projection ----------------
// grid 2048 (64 rows each), 256 thr. C = [64 x 512] (outs 0..255 keys, 256..511 values)
// keys stored [b][n][d] bf16; values stored TRANSPOSED vT[b][d][n] bf16.
__global__ __launch_bounds__(256) void k1(const float* __restrict__ emb,
                                          const unsigned short* __restrict__ Wswz,
                                          const float* __restrict__ lng, const float* __restrict__ lnb,
                                          unsigned short* __restrict__ keys, unsigned short* __restrict__ vT){
  __shared__ __align__(16) char xl[32768];          // LN(x) tile [64][256] bf16, swizzled
  __shared__ __align__(16) char wl[32768];          // weight chunk [64][256] bf16, swizzled
  __shared__ __align__(16) unsigned short st[64*72]; // epilogue repack
  int t = threadIdx.x, blk = blockIdx.x;
  int w = t>>6, l = t&63;
  int l15 = l&15, lg = l>>4;
  {
    int r = t>>2, q4 = t&3;
    const float* erow = emb + ((size_t)blk*64 + r)*256 + q4*64;
    float v[64];
    float sum=0.f, sq=0.f;
    #pragma unroll
    for (int jj=0;jj<16;++jj){
      float4 f = *(const float4*)(erow + jj*4);
      v[jj*4+0]=f.x; v[jj*4+1]=f.y; v[jj*4+2]=f.z; v[jj*4+3]=f.w;
      sum += f.x+f.y+f.z+f.w;
      sq  += f.x*f.x + f.y*f.y + f.z*f.z + f.w*f.w;
    }
    sum += __shfl_xor(sum,1); sq += __shfl_xor(sq,1);
    sum += __shfl_xor(sum,2); sq += __shfl_xor(sq,2);
    float m = sum*(1.f/256.f);
    float var = sq*(1.f/256.f) - m*m;
    float inv = rsqrtf(fmaxf(var,0.f) + 1e-5f);
    int swz = (r&7)<<4;
    #pragma unroll
    for (int jj=0;jj<16;++jj){
      int d0 = q4*64 + jj*4;
      float4 g4 = *(const float4*)(lng + d0);
      float4 b4 = *(const float4*)(lnb + d0);
      ushort4 p;
      p.x = f2b((v[jj*4+0]-m)*inv*g4.x + b4.x);
      p.y = f2b((v[jj*4+1]-m)*inv*g4.y + b4.y);
      p.z = f2b((v[jj*4+2]-m)*inv*g4.z + b4.z);
      p.w = f2b((v[jj*4+3]-m)*inv*g4.w + b4.w);
      int cc16 = q4*128 + (jj>>1)*16;
      *(ushort4*)(xl + r*512 + (cc16 ^ swz) + (jj&1)*8) = p;
    }
  }
  size_t bb = blk>>6;          // batch
  int n0b = (blk&63)*64;       // n offset within batch
  #pragma unroll 1
  for (int c=0;c<8;++c){
    const char* wsrc = (const char*)Wswz + (size_t)c*32768 + w*8192 + l*16;
    char* wdst = wl + w*8192;
    #pragma unroll
    for (int i=0;i<8;++i) glds16(wsrc + i*1024, wdst + i*1024);
    asm volatile("s_waitcnt vmcnt(0)" ::: "memory");
    __syncthreads();
    f32x4 z4 = {0.f,0.f,0.f,0.f};
    f32x4 acc[4] = {z4,z4,z4,z4};
    int brow = 16*w + l15; int bswz = (brow&7)<<4;
    int aswz = (l15&7)<<4;
    #pragma unroll
    for (int s=0;s<8;++s){
      int ck = (lg<<4) + (s<<6);
      short8 bf = *(const short8*)(wl + brow*512 + (ck ^ bswz));
      int axor = ck ^ aswz;
      #pragma unroll
      for (int mt=0;mt<4;++mt){
        short8 af = *(const short8*)(xl + (16*mt + l15)*512 + axor);
        acc[mt] = __builtin_amdgcn_mfma_f32_16x16x32_bf16(af, bf, acc[mt], 0,0,0);
      }
    }
    // epilogue: repack C tile through LDS for coalesced global stores
    if (c < 4){
      #pragma unroll
      for (int mt=0;mt<4;++mt){
        int m0 = 16*mt + (lg<<2);
        int co = 16*w + l15;
        st[(m0+0)*72 + co] = f2b(acc[mt][0]);
        st[(m0+1)*72 + co] = f2b(acc[mt][1]);
        st[(m0+2)*72 + co] = f2b(acc[mt][2]);
        st[(m0+3)*72 + co] = f2b(acc[mt][3]);
      }
    } else {
      #pragma unroll
      for (int mt=0;mt<4;++mt){
        int co = 16*w + l15;
        int m0 = 16*mt + (lg<<2);
        ushort4 p; p.x=f2b(acc[mt][0]); p.y=f2b(acc[mt][1]); p.z=f2b(acc[mt][2]); p.w=f2b(acc[mt][3]);
        *(ushort4*)(st + co*72 + m0) = p;
      }
    }
    __syncthreads();
    {
      int row2 = t>>2, seg = t&3;
      int4 d0 = *(const int4*)(st + row2*72 + seg*16);
      int4 d1 = *(const int4*)(st + row2*72 + seg*16 + 8);
      if (c < 4){
        size_t off = ((size_t)blk*64 + row2)*256 + c*64 + seg*16;
        *(int4*)(keys + off)     = d0;
        *(int4*)(keys + off + 8) = d1;
      } else {
        size_t off = (bb*256 + (size_t)(c-4)*64 + row2)*4096 + n0b + seg*16;
        *(int4*)(vT + off)     = d0;
        *(int4*)(vT + off + 8) = d1;
      }
    }
  }
}

// ---------------- k3: dots -> softmax(K) -> partial S / unnormalized updates ----------------
// grid 512 = 32 b x 16 n-blocks of 256 n; 256 thr (4 waves). Flash-style, MFMA both GEMMs.
__global__ __launch_bounds__(256) void k3(const unsigned short* __restrict__ keys,
                                          const unsigned short* __restrict__ vT,
                                          const unsigned short* __restrict__ qbuf,
                                          float* __restrict__ U, float* __restrict__ S,
                                          float* __restrict__ outA, int last){
  __shared__ __align__(16) char kl[32768];   // [64 n][256 d] bf16, swizzled
  __shared__ __align__(16) char vl[32768];   // [256 d][64 n] bf16, swizzled
  __shared__ __align__(16) char al[2048];    // attn [16][64] bf16, swizzled
  int t = threadIdx.x, w = t>>6, l = t&63;
  int l15 = l&15, lg = l>>4;
  int b = blockIdx.x >> 4;
  int nbase = (blockIdx.x & 15) << 8;
  if (t < 128){ int4 zz = {0,0,0,0}; ((int4*)al)[t] = zz; }  // rows 8..15 stay zero
  short8 qf[8];
  const unsigned short* qb = qbuf + (size_t)b*4096;
  #pragma unroll
  for (int s=0;s<8;++s)
    qf[s] = *(const short8*)(qb + l15*256 + (lg<<3) + (s<<5));
  f32x4 z4 = {0.f,0.f,0.f,0.f};
  f32x4 upd[4] = {z4,z4,z4,z4};
  float sp[4] = {0.f,0.f,0.f,0.f};
  const char* kbase = (const char*)(keys + ((size_t)b*4096 + nbase)*256);
  const char* vbase = (const char*)(vT + (size_t)b*1048576 + nbase);
  #pragma unroll 1
  for (int sub=0; sub<4; ++sub){
    {
      const char* ks = kbase + (size_t)sub*32768;
      char* kd = kl + w*8192;
      #pragma unroll
      for (int i=0;i<8;++i){
        int A = w*8192 + i*1024 + l*16;
        int row = A>>9, cc = A&511;
        glds16(ks + row*512 + (cc ^ ((row&7)<<4)), kd + i*1024);
      }
      const char* vs = vbase + sub*128;
      char* vd = vl + w*8192;
      #pragma unroll
      for (int i=0;i<8;++i){
        int A = w*8192 + i*1024 + l*16;
        int row = A>>7, cc = A&127;
        glds16(vs + (size_t)row*8192 + (cc ^ ((row&7)<<4)), vd + i*1024);
      }
    }
    asm volatile("s_waitcnt vmcnt(0)" ::: "memory");
    __syncthreads();
    // dots: this wave's 16 n-columns (w*16..w*16+15); A=q (regs), B=k tile
    f32x4 dacc = z4;
    int krow = w*16 + l15; int kswz = (krow&7)<<4;
    #pragma unroll
    for (int s=0;s<8;++s){
      int ck = (lg<<4) + (s<<6);
      short8 bf = *(const short8*)(kl + krow*512 + (ck ^ kswz));
      dacc = __builtin_amdgcn_mfma_f32_16x16x32_bf16(qf[s], bf, dacc, 0,0,0);
    }
    // softmax over the 8 slots per n (slots 0-3 in lanes 0-15, 4-7 in lanes 16-31)
    float d0=dacc[0], d1=dacc[1], d2=dacc[2], d3=dacc[3];
    float mx = fmaxf(fmaxf(d0,d1), fmaxf(d2,d3));
    mx = fmaxf(mx, __shfl_xor(mx,16));
    float e0=__expf(d0-mx), e1=__expf(d1-mx), e2=__expf(d2-mx), e3=__expf(d3-mx);
    float se = e0+e1+e2+e3;
    se += __shfl_xor(se,16);
    float inv = 1.f/se;
    float a0=e0*inv+1e-8f, a1=e1*inv+1e-8f, a2=e2*inv+1e-8f, a3=e3*inv+1e-8f;
    if (l < 32){
      sp[0]+=a0; sp[1]+=a1; sp[2]+=a2; sp[3]+=a3;
      int rr = lg<<2;
      int nc2 = (w*16 + l15)*2;
      *(unsigned short*)(al + (rr+0)*128 + (nc2 ^ ((rr+0)<<4))) = f2b(a0);
      *(unsigned short*)(al + (rr+1)*128 + (nc2 ^ ((rr+1)<<4))) = f2b(a1);
      *(unsigned short*)(al + (rr+2)*128 + (nc2 ^ ((rr+2)<<4))) = f2b(a2);
      *(unsigned short*)(al + (rr+3)*128 + (nc2 ^ ((rr+3)<<4))) = f2b(a3);
      if (last){
        size_t o = ((size_t)b*8 + rr)*4096 + nbase + sub*64 + w*16 + l15;
        outA[o] = a0; outA[o+4096]=a1; outA[o+8192]=a2; outA[o+12288]=a3;
      }
    }
    __syncthreads();
    // updates: A=attn [16 x 64n], B=vT tile; wave owns d-tiles 4w..4w+3
    #pragma unroll
    for (int s2=0;s2<2;++s2){
      int ck = (lg<<4) + (s2<<6);
      short8 af = *(const short8*)(al + l15*128 + (ck ^ ((l15&7)<<4)));
      #pragma unroll
      for (int dt=0;dt<4;++dt){
        int vrow = (4*w+dt)*16 + l15;
        short8 bf = *(const short8*)(vl + vrow*128 + (ck ^ ((vrow&7)<<4)));
        upd[dt] = __builtin_amdgcn_mfma_f32_16x16x32_bf16(af, bf, upd[dt], 0,0,0);
      }
    }
    __syncthreads();
  }
  #pragma unroll
  for (int j=0;j<4;++j){
    sp[j] += __shfl_xor(sp[j],1);
    sp[j] += __shfl_xor(sp[j],2);
    sp[j] += __shfl_xor(sp[j],4);
    sp[j] += __shfl_xor(sp[j],8);
  }
  if (l15==0 && l<32){
    int rr = lg<<2;
    atomicAdd(&S[b*8+rr+0], sp[0]);
    atomicAdd(&S[b*8+rr+1], sp[1]);
    atomicAdd(&S[b*8+rr+2], sp[2]);
    atomicAdd(&S[b*8+rr+3], sp[3]);
  }
  if (l < 32){
    int rr = lg<<2;
    #pragma unroll
    for (int dt=0;dt<4;++dt){
      int d = (4*w+dt)*16 + l15;
      atomicAdd(&U[((size_t)b*8+rr+0)*256 + d], upd[dt][0]);
      atomicAdd(&U[((size_t)b*8+rr+1)*256 + d], upd[dt][1]);
      atomicAdd(&U[((size_t)b*8+rr+2)*256 + d], upd[dt][2]);
      atomicAdd(&U[((size_t)b*8+rr+3)*256 + d], upd[dt][3]);
    }
  }
}

// ---------------- k4: GRU + residual MLP + next queries ----------------
// grid 256 (one block per slot-row), 256 thr (t = d index and out index)
__global__ void k4(float* __restrict__ U, float* __restrict__ S, float* __restrict__ slots,
                   const float* __restrict__ bih, const float* __restrict__ bhh,
                   const unsigned short* __restrict__ Wihb, const unsigned short* __restrict__ Whhb,
                   const unsigned short* __restrict__ W1b, const unsigned short* __restrict__ W2b,
                   const unsigned short* __restrict__ Wqb,
                   const float* __restrict__ pb1, const float* __restrict__ pb2,
                   const float* __restrict__ lnfg, const float* __restrict__ lnfb,
                   const float* __restrict__ lnsg, const float* __restrict__ lnsb,
                   unsigned short* __restrict__ qbuf, float* __restrict__ outS, int last){
  __shared__ __align__(16) float uh[512];
  __shared__ __align__(16) float yl[256];
  __shared__ __align__(16) float y1l[256];
  __shared__ float red[8];
  int r = blockIdx.x, t = threadIdx.x;
  float Sr = S[r];
  float u = U[r*256 + t] / Sr;
  float h = slots[r*256 + t];
  uh[t] = u; uh[256 + t] = h;
  __syncthreads();
  U[r*256 + t] = 0.f;           // reset accumulators for next iteration
  if (t == 0) S[r] = 0.f;
  float gir = bih[t], giz = bih[256+t], gin = bih[512+t];
  float ghr = bhh[t], ghz = bhh[256+t], ghn = bhh[512+t];
  {
    const unsigned short* p0 = Wihb + (size_t)t*256;
    const unsigned short* p1 = Wihb + (size_t)(256+t)*256;
    const unsigned short* p2 = Wihb + (size_t)(512+t)*256;
    const unsigned short* p3 = Whhb + (size_t)t*256;
    const unsigned short* p4 = Whhb + (size_t)(256+t)*256;
    const unsigned short* p5 = Whhb + (size_t)(512+t)*256;
    #pragma unroll 2
    for (int c=0;c<32;++c){
      const float* ux = uh + c*8;
      const float* hx = uh + 256 + c*8;
      gir += dot8(*(const short8*)(p0 + c*8), ux);
      giz += dot8(*(const short8*)(p1 + c*8), ux);
      gin += dot8(*(const short8*)(p2 + c*8), ux);
      ghr += dot8(*(const short8*)(p3 + c*8), hx);
      ghz += dot8(*(const short8*)(p4 + c*8), hx);
      ghn += dot8(*(const short8*)(p5 + c*8), hx);
    }
  }
  float rg = 1.f/(1.f+__expf(-(gir+ghr)));
  float zz = 1.f/(1.f+__expf(-(giz+ghz)));
  float ng = tanhf(gin + rg*ghn);
  float s1 = (1.f-zz)*ng + zz*h;
  // LN_ff
  float sa = s1, sb = s1*s1;
  bred2(sa, sb, red);
  float m = sa*(1.f/256.f);
  float var = sb*(1.f/256.f) - m*m;
  float yv = (s1-m)*rsqrtf(fmaxf(var,0.f)+1e-5f)*lnfg[t] + lnfb[t];
  yl[t] = yv;
  __syncthreads();
  float a1 = pb1[t];
  const unsigned short* q1 = W1b + (size_t)t*256;
  #pragma unroll 2
  for (int c=0;c<32;++c) a1 += dot8(*(const short8*)(q1 + c*8), yl + c*8);
  float y1 = (a1 > 0.f) ? a1 : 0.01f*a1;
  y1l[t] = y1;
  __syncthreads();
  float a2 = pb2[t];
  const unsigned short* q2 = W2b + (size_t)t*256;
  #pragma unroll 2
  for (int c=0;c<32;++c) a2 += dot8(*(const short8*)(q2 + c*8), y1l + c*8);
  float s2v = s1 + a2;
  slots[r*256 + t] = s2v;
  if (last){
    outS[r*256 + t] = s2v;
  } else {
    float ta = s2v, tb = s2v*s2v;
    bred2(ta, tb, red);
    float m2 = ta*(1.f/256.f);
    float v2 = tb*(1.f/256.f) - m2*m2;
    float snv = (s2v - m2)*rsqrtf(fmaxf(v2,0.f)+1e-5f)*lnsg[t] + lnsb[t];
    __syncthreads();
    yl[t] = snv;
    __syncthreads();
    float aq = 0.f;
    const unsigned short* q3 = Wqb + (size_t)t*256;
    #pragma unroll 2
    for (int c=0;c<32;++c) aq += dot8(*(const short8*)(q3 + c*8), yl + c*8);
    qbuf[((r>>3)*16 + (r&7))*256 + t] = f2b(aq * 0.0625f);
  }
}

extern "C" void kernel_launch(void* const* d_in, const int* in_sizes, int n_in,
                              void* d_out, int out_size, void* d_ws, size_t ws_size,
                              hipStream_t stream) {
  (void)in_sizes; (void)n_in; (void)out_size; (void)ws_size;
  const float* emb  = (const float*)d_in[0];
  const float* noise= (const float*)d_in[1];
  const float* mu   = (const float*)d_in[2];
  const float* ls   = (const float*)d_in[3];
  const float* Wq   = (const float*)d_in[4];
  const float* Wk   = (const float*)d_in[5];
  const float* Wv   = (const float*)d_in[6];
  const float* Wih  = (const float*)d_in[7];
  const float* Whh  = (const float*)d_in[8];
  const float* bih  = (const float*)d_in[9];
  const float* bhh  = (const float*)d_in[10];
  const float* W1   = (const float*)d_in[11];
  const float* b1   = (const float*)d_in[12];
  const float* W2   = (const float*)d_in[13];
  const float* b2   = (const float*)d_in[14];
  const float* lnig = (const float*)d_in[15];
  const float* lnib = (const float*)d_in[16];
  const float* lnsg = (const float*)d_in[17];
  const float* lnsb = (const float*)d_in[18];
  const float* lnfg = (const float*)d_in[19];
  const float* lnfb = (const float*)d_in[20];

  unsigned short* keys = (unsigned short*)d_ws;      // 33554432 elems
  unsigned short* vT   = keys + 33554432;            // 33554432
  unsigned short* Wswz = vT + 33554432;              // 131072
  unsigned short* Wihb = Wswz + 131072;              // 196608
  unsigned short* Whhb = Wihb + 196608;              // 196608
  unsigned short* W1b  = Whhb + 196608;              // 65536
  unsigned short* W2b  = W1b + 65536;                // 65536
  unsigned short* Wqb  = W2b + 65536;                // 65536
  unsigned short* qbuf = Wqb + 65536;                // 131072 (32 x 16 x 256, rows 8-15 zero)
  float* slots = (float*)(qbuf + 131072);            // 65536 floats
  float* U = slots + 65536;                          // 65536
  float* S = U + 65536;                              // 256
  float* outS = (float*)d_out;
  float* outA = outS + 65536;

  k_prep<<<832, 256, 0, stream>>>(Wk, Wv, Wih, Whh, W1, W2, Wq,
                                  Wswz, Wihb, Whhb, W1b, W2b, Wqb);
  k_init<<<256, 256, 0, stream>>>(noise, mu, ls, lnsg, lnsb, Wqb, slots, U, S, qbuf);
  k1<<<2048, 256, 0, stream>>>(emb, Wswz, lnig, lnib, keys, vT);
  for (int it=0; it<3; ++it){
    int lastf = (it==2) ? 1 : 0;
    k3<<<512, 256, 0, stream>>>(keys, vT, qbuf, U, S, outA, lastf);
    k4<<<256, 256, 0, stream>>>(U, S, slots, bih, bhh, Wihb, Whhb, W1b, W2b, Wqb,
                                b1, b2, lnfg, lnfb, lnsg, lnsb, qbuf, outS, lastf);
  }
}

// Round 2
// 599.446 us; speedup vs baseline: 1.0243x; 1.0243x over previous
//
#include <hip/hip_runtime.h>
#include <hip/hip_bf16.h>

typedef __attribute__((ext_vector_type(8))) short short8;
typedef __attribute__((ext_vector_type(4))) float f32x4;

#define DI __device__ __forceinline__

DI unsigned short f2b(float f){
  union{float ff; unsigned u;} v; v.ff=f;
  unsigned r = v.u;
  r += 0x7fffu + ((r>>16)&1u);   // RNE
  return (unsigned short)(r>>16);
}
DI float b2f(unsigned short h){
  union{unsigned u; float ff;} v; v.u = ((unsigned)h)<<16; return v.ff;
}

DI float dot8(short8 wv, const float* x){
  float s = 0.f;
  #pragma unroll
  for (int i=0;i<8;++i) s += b2f((unsigned short)wv[i]) * x[i];
  return s;
}

// block-wide (256 thr) sum of two values
DI void bred2(float& a, float& b, float* red){
  #pragma unroll
  for (int o=32;o>0;o>>=1){ a += __shfl_xor(a,o); b += __shfl_xor(b,o); }
  int wid = threadIdx.x>>6;
  __syncthreads();
  if ((threadIdx.x&63)==0){ red[wid*2]=a; red[wid*2+1]=b; }
  __syncthreads();
  a = red[0]+red[2]+red[4]+red[6];
  b = red[1]+red[3]+red[5]+red[7];
}

// ---------------- k0: weight bf16 conversion (blocks 0..703) + slot init/q0 (blocks 704..959) ----
__global__ void k0(const float* __restrict__ Wk, const float* __restrict__ Wv,
                   const float* __restrict__ Wih, const float* __restrict__ Whh,
                   const float* __restrict__ W1, const float* __restrict__ W2,
                   const float* __restrict__ Wq,
                   unsigned short* Wkvb, unsigned short* Wihb, unsigned short* Whhb,
                   unsigned short* W1b, unsigned short* W2b, unsigned short* Wqb,
                   const float* __restrict__ noise, const float* __restrict__ mu,
                   const float* __restrict__ ls, const float* __restrict__ lnsg,
                   const float* __restrict__ lnsb,
                   float* slots, unsigned short* qbuf){
  __shared__ __align__(16) float sn[256];
  __shared__ float red[8];
  int t = threadIdx.x, blk = blockIdx.x;
  if (blk < 704){
    int j = blk*1024 + t*4;
    const float* sp; unsigned short* dp;
    if (j < 65536){ sp=Wk+j; dp=Wkvb+j; }
    else if (j < 131072){ sp=Wv+(j-65536); dp=Wkvb+j; }
    else if (j < 327680){ sp=Wih+(j-131072); dp=Wihb+(j-131072); }
    else if (j < 524288){ sp=Whh+(j-327680); dp=Whhb+(j-327680); }
    else if (j < 589824){ sp=W1+(j-524288); dp=W1b+(j-524288); }
    else if (j < 655360){ sp=W2+(j-589824); dp=W2b+(j-589824); }
    else { sp=Wq+(j-655360); dp=Wqb+(j-655360); }
    float4 v = *(const float4*)sp;
    dp[0]=f2b(v.x); dp[1]=f2b(v.y); dp[2]=f2b(v.z); dp[3]=f2b(v.w);
  } else {
    int r = blk - 704;
    int b = r>>3, k = r&7;
    float val = mu[t] + __expf(ls[t]) * noise[r*256 + t];
    slots[r*256 + t] = val;
    qbuf[(b*16 + 8 + k)*256 + t] = 0;      // zero q pad rows (slots 8..15)
    float sa = val, sb = val*val;
    bred2(sa, sb, red);
    float m = sa*(1.f/256.f);
    float var = sb*(1.f/256.f) - m*m;
    float inv = rsqrtf(fmaxf(var, 0.f) + 1e-5f);
    sn[t] = (val - m)*inv*lnsg[t] + lnsb[t];
    __syncthreads();
    const float* wr = Wq + (size_t)t*256;
    float acc = 0.f;
    #pragma unroll 8
    for (int c=0;c<64;++c){
      float4 wv = *(const float4*)(wr + c*4);
      acc += wv.x*sn[c*4] + wv.y*sn[c*4+1] + wv.z*sn[c*4+2] + wv.w*sn[c*4+3];
    }
    qbuf[(b*16 + k)*256 + t] = f2b(acc * 0.0625f);   // SCALE folded in
  }
}

// ---------------- k1: LN(embeddings) + keys/values projection ----------------
// grid 2048 (64 n-rows each), 256 thr. Outputs 0..255 keys [b][n][d]; 256..511 values
// stored TRANSPOSED vT[b][d][n]. B-fragments read directly from global (L2-hot).
__global__ __launch_bounds__(256) void k1(const float* __restrict__ emb,
                                          const unsigned short* __restrict__ Wkvb,
                                          const float* __restrict__ lng, const float* __restrict__ lnb,
                                          unsigned short* __restrict__ keys, unsigned short* __restrict__ vT){
  __shared__ __align__(16) char xl[32768];           // LN(x) [64][256] bf16, 5-bit chunk swizzle
  __shared__ __align__(16) unsigned short st[64*72]; // epilogue repack
  int t = threadIdx.x, blk = blockIdx.x;
  int w = t>>6, l = t&63, l15 = l&15, lg = l>>4;
  {
    int r = t>>2, q4 = t&3;
    const float* erow = emb + ((size_t)blk*64 + r)*256 + q4*64;
    float v[64];
    float sum=0.f, sq=0.f;
    #pragma unroll
    for (int jj=0;jj<16;++jj){
      float4 f = *(const float4*)(erow + jj*4);
      v[jj*4+0]=f.x; v[jj*4+1]=f.y; v[jj*4+2]=f.z; v[jj*4+3]=f.w;
      sum += f.x+f.y+f.z+f.w;
      sq  += f.x*f.x + f.y*f.y + f.z*f.z + f.w*f.w;
    }
    sum += __shfl_xor(sum,1); sq += __shfl_xor(sq,1);
    sum += __shfl_xor(sum,2); sq += __shfl_xor(sq,2);
    float m = sum*(1.f/256.f);
    float var = sq*(1.f/256.f) - m*m;
    float inv = rsqrtf(fmaxf(var,0.f) + 1e-5f);
    int r7 = r&7;
    #pragma unroll
    for (int jp=0;jp<8;++jp){
      int d0 = q4*64 + jp*8;
      float4 g0 = *(const float4*)(lng + d0); float4 g1 = *(const float4*)(lng + d0 + 4);
      float4 b0 = *(const float4*)(lnb + d0); float4 b1 = *(const float4*)(lnb + d0 + 4);
      short8 pk;
      pk[0]=(short)f2b((v[jp*8+0]-m)*inv*g0.x + b0.x);
      pk[1]=(short)f2b((v[jp*8+1]-m)*inv*g0.y + b0.y);
      pk[2]=(short)f2b((v[jp*8+2]-m)*inv*g0.z + b0.z);
      pk[3]=(short)f2b((v[jp*8+3]-m)*inv*g0.w + b0.w);
      pk[4]=(short)f2b((v[jp*8+4]-m)*inv*g1.x + b1.x);
      pk[5]=(short)f2b((v[jp*8+5]-m)*inv*g1.y + b1.y);
      pk[6]=(short)f2b((v[jp*8+6]-m)*inv*g1.z + b1.z);
      pk[7]=(short)f2b((v[jp*8+7]-m)*inv*g1.w + b1.w);
      int c16 = q4*8 + jp;
      *(short8*)(xl + r*512 + ((c16 ^ r7)<<4)) = pk;
    }
  }
  __syncthreads();
  size_t bb = blk>>6;          // batch
  int n0b = (blk&63)*64;       // n offset within batch
  int swz = l15&7;
  #pragma unroll 1
  for (int c=0;c<8;++c){
    const unsigned short* wp = Wkvb + (size_t)(c*64 + 16*w + l15)*256 + lg*8;
    short8 bf[8];
    #pragma unroll
    for (int s=0;s<8;++s) bf[s] = *(const short8*)(wp + s*32);
    f32x4 z4 = {0.f,0.f,0.f,0.f};
    f32x4 acc[4] = {z4,z4,z4,z4};
    #pragma unroll
    for (int s=0;s<8;++s){
      int pc = ((lg + s*4) ^ swz)<<4;
      #pragma unroll
      for (int mt=0;mt<4;++mt){
        short8 af = *(const short8*)(xl + (16*mt + l15)*512 + pc);
        acc[mt] = __builtin_amdgcn_mfma_f32_16x16x32_bf16(af, bf[s], acc[mt], 0,0,0);
      }
    }
    __syncthreads();   // st free from previous chunk's reads
    if (c < 4){
      #pragma unroll
      for (int mt=0;mt<4;++mt){
        int m0 = 16*mt + (lg<<2);
        int co = 16*w + l15;
        st[(m0+0)*72 + co] = f2b(acc[mt][0]);
        st[(m0+1)*72 + co] = f2b(acc[mt][1]);
        st[(m0+2)*72 + co] = f2b(acc[mt][2]);
        st[(m0+3)*72 + co] = f2b(acc[mt][3]);
      }
    } else {
      #pragma unroll
      for (int mt=0;mt<4;++mt){
        int co = 16*w + l15;
        int m0 = 16*mt + (lg<<2);
        ushort4 p; p.x=f2b(acc[mt][0]); p.y=f2b(acc[mt][1]); p.z=f2b(acc[mt][2]); p.w=f2b(acc[mt][3]);
        *(ushort4*)(st + co*72 + m0) = p;
      }
    }
    __syncthreads();
    {
      int row2 = t>>2, seg = t&3;
      int4 d0 = *(const int4*)(st + row2*72 + seg*16);
      int4 d1 = *(const int4*)(st + row2*72 + seg*16 + 8);
      if (c < 4){
        size_t off = ((size_t)blk*64 + row2)*256 + c*64 + seg*16;
        *(int4*)(keys + off)     = d0;
        *(int4*)(keys + off + 8) = d1;
      } else {
        size_t off = (bb*256 + (size_t)(c-4)*64 + row2)*4096 + n0b + seg*16;
        *(int4*)(vT + off)     = d0;
        *(int4*)(vT + off + 8) = d1;
      }
    }
  }
}

// ---------------- k3: dots -> softmax(K) -> partial S / unnormalized updates ----------------
// grid 1024 = 32 b x 32 n-blocks of 128 n; 256 thr (4 waves). K/vT fragments read
// directly from global (streamed, 64B-coalesced). Partial sums stored per block (no atomics).
__global__ __launch_bounds__(256) void k3(const unsigned short* __restrict__ keys,
                                          const unsigned short* __restrict__ vT,
                                          const unsigned short* __restrict__ qbuf,
                                          float* __restrict__ Upart, float* __restrict__ Spart,
                                          float* __restrict__ outA, int last){
  __shared__ __align__(16) char al[2][2048];   // attn [16 slots][64 n] bf16, swizzled, dbuf
  __shared__ float sS[4][8];
  int t = threadIdx.x, w = t>>6, l = t&63;
  int l15 = l&15, lg = l>>4;
  int b = blockIdx.x >> 5;
  int n0 = (blockIdx.x & 31) << 7;
  { int4 zz = {0,0,0,0}; ((int4*)al)[t&255] = zz; }  // zero both buffers (pad rows 8..15 stay 0)
  short8 qf[8];
  const unsigned short* qb = qbuf + (size_t)b*4096 + l15*256 + lg*8;
  #pragma unroll
  for (int s=0;s<8;++s) qf[s] = *(const short8*)(qb + s*32);
  f32x4 z4 = {0.f,0.f,0.f,0.f};
  f32x4 upd[4] = {z4,z4,z4,z4};
  float sp[4] = {0.f,0.f,0.f,0.f};
  const unsigned short* kb = keys + ((size_t)b*4096 + n0)*256;
  const unsigned short* vb = vT + (size_t)b*1048576 + n0;
  __syncthreads();
  #pragma unroll 1
  for (int sub=0; sub<2; ++sub){
    int nc = sub*64;
    // dots: A = q (regs), B = key rows from global
    const unsigned short* kr = kb + (size_t)(nc + 16*w + l15)*256 + lg*8;
    short8 kf[8];
    #pragma unroll
    for (int s=0;s<8;++s) kf[s] = *(const short8*)(kr + s*32);
    f32x4 dacc = z4;
    #pragma unroll
    for (int s=0;s<8;++s)
      dacc = __builtin_amdgcn_mfma_f32_16x16x32_bf16(qf[s], kf[s], dacc, 0,0,0);
    // softmax over 8 slots per n (slots 0-3 lanes 0-15 regs, 4-7 lanes 16-31)
    float d0=dacc[0], d1=dacc[1], d2=dacc[2], d3=dacc[3];
    float mx = fmaxf(fmaxf(d0,d1), fmaxf(d2,d3));
    mx = fmaxf(mx, __shfl_xor(mx,16));
    float e0=__expf(d0-mx), e1=__expf(d1-mx), e2=__expf(d2-mx), e3=__expf(d3-mx);
    float se = e0+e1+e2+e3;
    se += __shfl_xor(se,16);
    float inv = 1.f/se;
    float a0=e0*inv+1e-8f, a1=e1*inv+1e-8f, a2=e2*inv+1e-8f, a3=e3*inv+1e-8f;
    char* alp = al[sub];
    if (l < 32){
      sp[0]+=a0; sp[1]+=a1; sp[2]+=a2; sp[3]+=a3;
      int rr = lg<<2;
      int nc2 = (w*16 + l15)*2;
      *(unsigned short*)(alp + (rr+0)*128 + (nc2 ^ ((rr+0)<<4))) = f2b(a0);
      *(unsigned short*)(alp + (rr+1)*128 + (nc2 ^ ((rr+1)<<4))) = f2b(a1);
      *(unsigned short*)(alp + (rr+2)*128 + (nc2 ^ ((rr+2)<<4))) = f2b(a2);
      *(unsigned short*)(alp + (rr+3)*128 + (nc2 ^ ((rr+3)<<4))) = f2b(a3);
      if (last){
        size_t o = ((size_t)b*8 + rr)*4096 + n0 + nc + w*16 + l15;
        outA[o] = a0; outA[o+4096]=a1; outA[o+8192]=a2; outA[o+12288]=a3;
      }
    }
    __syncthreads();
    // updates: A = attn [16 x 64n] from LDS, B = vT rows from global
    #pragma unroll
    for (int s2=0;s2<2;++s2){
      int ck = (lg<<4) + (s2<<6);
      short8 af = *(const short8*)(alp + l15*128 + (ck ^ ((l15&7)<<4)));
      #pragma unroll
      for (int dt=0;dt<4;++dt){
        const unsigned short* vr = vb + (size_t)((4*w+dt)*16 + l15)*4096 + nc + s2*32 + lg*8;
        short8 bf = *(const short8*)vr;
        upd[dt] = __builtin_amdgcn_mfma_f32_16x16x32_bf16(af, bf, upd[dt], 0,0,0);
      }
    }
  }
  #pragma unroll
  for (int j=0;j<4;++j){
    sp[j] += __shfl_xor(sp[j],1);
    sp[j] += __shfl_xor(sp[j],2);
    sp[j] += __shfl_xor(sp[j],4);
    sp[j] += __shfl_xor(sp[j],8);
  }
  if (l15==0 && l<32){
    int rr = lg<<2;
    sS[w][rr+0]=sp[0]; sS[w][rr+1]=sp[1]; sS[w][rr+2]=sp[2]; sS[w][rr+3]=sp[3];
  }
  __syncthreads();
  if (t < 8) Spart[(size_t)blockIdx.x*8 + t] = sS[0][t]+sS[1][t]+sS[2][t]+sS[3][t];
  if (l < 32){
    int rr = lg<<2;
    float* up = Upart + (size_t)blockIdx.x*2048;
    #pragma unroll
    for (int dt=0;dt<4;++dt){
      int d = (4*w+dt)*16 + l15;
      up[(rr+0)*256 + d] = upd[dt][0];
      up[(rr+1)*256 + d] = upd[dt][1];
      up[(rr+2)*256 + d] = upd[dt][2];
      up[(rr+3)*256 + d] = upd[dt][3];
    }
  }
}

// ---------------- k4: partial-reduce + GRU + residual MLP + next queries ----------------
// grid 256 (one block per slot-row), 256 thr (t = d index and out index)
__global__ void k4(const float* __restrict__ Upart, const float* __restrict__ Spart,
                   float* __restrict__ slots,
                   const float* __restrict__ bih, const float* __restrict__ bhh,
                   const unsigned short* __restrict__ Wihb, const unsigned short* __restrict__ Whhb,
                   const unsigned short* __restrict__ W1b, const unsigned short* __restrict__ W2b,
                   const unsigned short* __restrict__ Wqb,
                   const float* __restrict__ pb1, const float* __restrict__ pb2,
                   const float* __restrict__ lnfg, const float* __restrict__ lnfb,
                   const float* __restrict__ lnsg, const float* __restrict__ lnsb,
                   unsigned short* __restrict__ qbuf, float* __restrict__ outS, int last){
  __shared__ __align__(16) float uh[512];
  __shared__ __align__(16) float yl[256];
  __shared__ __align__(16) float y1l[256];
  __shared__ float red[8];
  int r = blockIdx.x, t = threadIdx.x;
  int b = r>>3, k = r&7;
  float Sr = 0.f, u = 0.f;
  #pragma unroll 8
  for (int nb=0;nb<32;++nb){
    size_t bn = (size_t)(b*32 + nb);
    Sr += Spart[bn*8 + k];
    u  += Upart[bn*2048 + k*256 + t];
  }
  u /= Sr;
  float h = slots[r*256 + t];
  uh[t] = u; uh[256 + t] = h;
  __syncthreads();
  float gir = bih[t], giz = bih[256+t], gin = bih[512+t];
  float ghr = bhh[t], ghz = bhh[256+t], ghn = bhh[512+t];
  {
    const unsigned short* p0 = Wihb + (size_t)t*256;
    const unsigned short* p1 = Wihb + (size_t)(256+t)*256;
    const unsigned short* p2 = Wihb + (size_t)(512+t)*256;
    const unsigned short* p3 = Whhb + (size_t)t*256;
    const unsigned short* p4 = Whhb + (size_t)(256+t)*256;
    const unsigned short* p5 = Whhb + (size_t)(512+t)*256;
    #pragma unroll 2
    for (int c=0;c<32;++c){
      const float* ux = uh + c*8;
      const float* hx = uh + 256 + c*8;
      gir += dot8(*(const short8*)(p0 + c*8), ux);
      giz += dot8(*(const short8*)(p1 + c*8), ux);
      gin += dot8(*(const short8*)(p2 + c*8), ux);
      ghr += dot8(*(const short8*)(p3 + c*8), hx);
      ghz += dot8(*(const short8*)(p4 + c*8), hx);
      ghn += dot8(*(const short8*)(p5 + c*8), hx);
    }
  }
  float rg = 1.f/(1.f+__expf(-(gir+ghr)));
  float zz = 1.f/(1.f+__expf(-(giz+ghz)));
  float ng = tanhf(gin + rg*ghn);
  float s1 = (1.f-zz)*ng + zz*h;
  // LN_ff
  float sa = s1, sb = s1*s1;
  bred2(sa, sb, red);
  float m = sa*(1.f/256.f);
  float var = sb*(1.f/256.f) - m*m;
  float yv = (s1-m)*rsqrtf(fmaxf(var,0.f)+1e-5f)*lnfg[t] + lnfb[t];
  yl[t] = yv;
  __syncthreads();
  float a1 = pb1[t];
  const unsigned short* q1 = W1b + (size_t)t*256;
  #pragma unroll 2
  for (int c=0;c<32;++c) a1 += dot8(*(const short8*)(q1 + c*8), yl + c*8);
  float y1 = (a1 > 0.f) ? a1 : 0.01f*a1;
  y1l[t] = y1;
  __syncthreads();
  float a2 = pb2[t];
  const unsigned short* q2 = W2b + (size_t)t*256;
  #pragma unroll 2
  for (int c=0;c<32;++c) a2 += dot8(*(const short8*)(q2 + c*8), y1l + c*8);
  float s2v = s1 + a2;
  slots[r*256 + t] = s2v;
  if (last){
    outS[r*256 + t] = s2v;
  } else {
    float ta = s2v, tb = s2v*s2v;
    bred2(ta, tb, red);
    float m2 = ta*(1.f/256.f);
    float v2 = tb*(1.f/256.f) - m2*m2;
    float snv = (s2v - m2)*rsqrtf(fmaxf(v2,0.f)+1e-5f)*lnsg[t] + lnsb[t];
    __syncthreads();
    yl[t] = snv;
    __syncthreads();
    float aq = 0.f;
    const unsigned short* q3 = Wqb + (size_t)t*256;
    #pragma unroll 2
    for (int c=0;c<32;++c) aq += dot8(*(const short8*)(q3 + c*8), yl + c*8);
    qbuf[(b*16 + k)*256 + t] = f2b(aq * 0.0625f);
  }
}

extern "C" void kernel_launch(void* const* d_in, const int* in_sizes, int n_in,
                              void* d_out, int out_size, void* d_ws, size_t ws_size,
                              hipStream_t stream) {
  (void)in_sizes; (void)n_in; (void)out_size; (void)ws_size;
  const float* emb  = (const float*)d_in[0];
  const float* noise= (const float*)d_in[1];
  const float* mu   = (const float*)d_in[2];
  const float* ls   = (const float*)d_in[3];
  const float* Wq   = (const float*)d_in[4];
  const float* Wk   = (const float*)d_in[5];
  const float* Wv   = (const float*)d_in[6];
  const float* Wih  = (const float*)d_in[7];
  const float* Whh  = (const float*)d_in[8];
  const float* bih  = (const float*)d_in[9];
  const float* bhh  = (const float*)d_in[10];
  const float* W1   = (const float*)d_in[11];
  const float* b1   = (const float*)d_in[12];
  const float* W2   = (const float*)d_in[13];
  const float* b2   = (const float*)d_in[14];
  const float* lnig = (const float*)d_in[15];
  const float* lnib = (const float*)d_in[16];
  const float* lnsg = (const float*)d_in[17];
  const float* lnsb = (const float*)d_in[18];
  const float* lnfg = (const float*)d_in[19];
  const float* lnfb = (const float*)d_in[20];

  unsigned short* keys = (unsigned short*)d_ws;      // 33554432
  unsigned short* vT   = keys + 33554432;            // 33554432
  unsigned short* Wkvb = vT + 33554432;              // 131072
  unsigned short* Wihb = Wkvb + 131072;              // 196608
  unsigned short* Whhb = Wihb + 196608;              // 196608
  unsigned short* W1b  = Whhb + 196608;              // 65536
  unsigned short* W2b  = W1b + 65536;                // 65536
  unsigned short* Wqb  = W2b + 65536;                // 65536
  unsigned short* qbuf = Wqb + 65536;                // 131072
  float* slots = (float*)(qbuf + 131072);            // 65536 f32
  float* Upart = slots + 65536;                      // 2097152 f32
  float* Spart = Upart + 2097152;                    // 8192 f32
  float* outS = (float*)d_out;
  float* outA = outS + 65536;

  k0<<<960, 256, 0, stream>>>(Wk, Wv, Wih, Whh, W1, W2, Wq,
                              Wkvb, Wihb, Whhb, W1b, W2b, Wqb,
                              noise, mu, ls, lnsg, lnsb, slots, qbuf);
  k1<<<2048, 256, 0, stream>>>(emb, Wkvb, lnig, lnib, keys, vT);
  for (int it=0; it<3; ++it){
    int lastf = (it==2) ? 1 : 0;
    k3<<<1024, 256, 0, stream>>>(keys, vT, qbuf, Upart, Spart, outA, lastf);
    k4<<<256, 256, 0, stream>>>(Upart, Spart, slots, bih, bhh, Wihb, Whhb, W1b, W2b, Wqb,
                                b1, b2, lnfg, lnfb, lnsg, lnsb, qbuf, outS, lastf);
  }
}